// Round 16
// baseline (150.724 us; speedup 1.0000x reference)
//
#include <hip/hip_runtime.h>
#include <cmath>

#define WIN 11
#define HALO 5
#define IMG 512
#define NIMG 48
#define TS 64                         /* output tile: 64x64 */
#define HR (TS + 2*HALO)              /* 74 h-blurred rows held in LDS */
#define NTILE (IMG/TS)                /* 8 tiles per axis */
#define NTT (NIMG*NTILE*NTILE)        /* 3072 tiles total */
#define PBLK 512                      /* persistent blocks: ALL resident */
#define TPB (NTT/PBLK)                /* 6 tiles per block */
#define NPIX (16.0 * 3.0 * 512.0 * 512.0)

typedef _Float16 f16;
typedef _Float16 h2 __attribute__((ext_vector_type(2)));

/* packed fp16 {w,w} weights, built on host -> kernarg -> SGPR operands */
struct GaussW { unsigned hw[WIN]; };

__device__ __forceinline__ unsigned pk2(float a, float b) {
    auto h = __builtin_amdgcn_cvt_pkrtz(a, b);
    return __builtin_bit_cast(unsigned, h);
}
__device__ __forceinline__ h2 uph(unsigned u) {
    return __builtin_bit_cast(h2, u);
}
__device__ __forceinline__ unsigned dnh(h2 v) {
    return __builtin_bit_cast(unsigned, v);
}

/* barrier that orders LDS only: does NOT drain vmcnt, so register-prefetch
   global loads stay in flight across it. */
__device__ __forceinline__ void bar_lds() {
    asm volatile("s_waitcnt lgkmcnt(0)" ::: "memory");
    __builtin_amdgcn_s_barrier();
}

__global__ void __launch_bounds__(64) zero_kernel(float* out) {
    if (threadIdx.x == 0) out[0] = 0.f;
}

__global__ void __launch_bounds__(64) finish_kernel(float* out) {
    if (threadIdx.x == 0)
        out[0] = 1.0f - out[0] * (float)(1.0 / NPIX);
}

// ---- Persistent fused SSIM: 512-thr blocks, 2 CO-RESIDENT per CU ---------
// R15 post-mortem: dbuf+1-barrier gained only 6% (60.5us) -> the stall is
// the barrier SCOPE: one block-wide barrier still yokes all 16 waves of the
// CU into lock-step phases (all flood LDS together, all compute together).
// This version: 512-thread blocks, PBLK=512 -> ALL blocks resident (2/CU,
// observed 2-WG/CU cap; LDS 2x75.8KB=151.5KB fits).  The two co-resident
// blocks share no barrier: when A's waves sync/flood LDS, B's waves are
// mid-compute feeding the VALU, and vice versa.  Also removes the 2
// sequential block-rounds per CU (no restart/tail).
// Phase 1: 8 cols/thread x 64 rows (all 512 thr), rows 64..73 by thr
// 432..511 via a 2nd register buffer.  Phase 2: 2 rowgroups/thread.
// Identical per-pixel arithmetic to R10/R15.
template<int USE_ATOMIC>
__global__ void __launch_bounds__(512, 4) fused_ssim(
        const float* __restrict__ xin, const float* __restrict__ yin,
        float* __restrict__ outp, GaussW W) {
    __shared__ uint4 hb[2][HR][32];   /* 2 * 74 * 512B = 75,776 B */
    __shared__ float wsum[8];
    const int tid = threadIdx.x;
    /* phase-1 mapping: 8 cols/thread; pass0 rows 0..63 (all threads),
       pass1 rows 64..73 (threads 432..511, second buffer) */
    const int cg = tid & 7;
    const int r0_ = tid >> 3;         /* 0..63 */
    const bool p1 = (tid >= 432);
    const int r1_ = 64 + ((tid - 432) >> 3);   /* 64..73 for p1 threads */
    /* phase-2 mapping: 32 col-pair slots x 16 rowgroups, 2 groups/thread */
    const int idx    = tid & 31;
    const int rbaseA = (tid >> 5) * 2;         /* rowgroups 0..15 */
    const int rbaseB = rbaseA + 32;            /* rowgroups 16..31 */

    const int t0 = blockIdx.x * TPB;

    float xv0[18], yv0[18];           /* pass-0 prefetch buffer */
    float xv1[18], yv1[18];           /* pass-1 prefetch buffer (p1 only) */
    float local = 0.f;

    /* ---- issue global loads for tile t into register buffers ---- */
    auto prefetch = [&](int t) {
        const int tg  = t0 + t;
        const int img = tg >> 6;
        const int rem = tg & 63;
        const int ty  = rem >> 3;
        const int tx  = rem & 7;
        const float* xb = xin + (size_t)img * (IMG * IMG);
        const float* yb = yin + (size_t)img * (IMG * IMG);
        const int gx0 = tx * TS + cg * 8 - HALO;   /* 18-col window */
        const bool cint = (gx0 >= 0) && (gx0 + 17 < IMG);

        auto loadrow = [&](int r, float* xv, float* yv) {
            const int gy = ty * TS - HALO + r;
            const bool rowok = ((unsigned)gy < IMG);
            const float* xr = xb + (size_t)gy * IMG;
            const float* yr = yb + (size_t)gy * IMG;
            if (rowok && cint) {
                xv[0] = xr[gx0];  yv[0] = yr[gx0];
                #pragma unroll
                for (int q = 0; q < 4; ++q) {      /* 16B-aligned float4s */
                    float4 a = *(const float4*)(xr + gx0 + 1 + 4*q);
                    float4 b = *(const float4*)(yr + gx0 + 1 + 4*q);
                    xv[1+4*q]=a.x; xv[2+4*q]=a.y; xv[3+4*q]=a.z; xv[4+4*q]=a.w;
                    yv[1+4*q]=b.x; yv[2+4*q]=b.y; yv[3+4*q]=b.z; yv[4+4*q]=b.w;
                }
                xv[17] = xr[gx0 + 17];  yv[17] = yr[gx0 + 17];
            } else {
                #pragma unroll
                for (int j = 0; j < 18; ++j) {
                    int gx = gx0 + j;
                    bool ok = rowok && ((unsigned)gx < IMG);
                    xv[j] = ok ? xr[gx] : 0.f;
                    yv[j] = ok ? yr[gx] : 0.f;
                }
            }
        };
        loadrow(r0_, xv0, yv0);
        if (p1) loadrow(r1_, xv1, yv1);
    };

    /* ---- packed fp16 h-blur of one register window -> LDS row ---- */
    auto hrow = [&](int b, int r, const float* xv, const float* yv) {
        h2 a0[8], a1[8];
        #pragma unroll
        for (int o = 0; o < 8; ++o) {
            a0[o] = (h2){(f16)0, (f16)0};
            a1[o] = (h2){(f16)0, (f16)0};
        }
        #pragma unroll
        for (int j = 0; j < 18; ++j) {
            float xs = xv[j], ys = yv[j];
            h2 c0 = uph(pk2(xs, ys));
            h2 c1 = uph(pk2(fmaf(xs, xs, ys * ys), xs * ys));
            #pragma unroll
            for (int o = 0; o < 8; ++o) {
                int k = j - o;
                if (k >= 0 && k < WIN) {
                    h2 wk = uph(W.hw[k]);          /* SGPR operand */
                    a0[o] += wk * c0;
                    a1[o] += wk * c1;
                }
            }
        }
        #pragma unroll
        for (int p = 0; p < 4; ++p) {
            uint4 u;
            u.x = dnh(a0[2*p]);     u.y = dnh(a1[2*p]);
            u.z = dnh(a0[2*p + 1]); u.w = dnh(a1[2*p + 1]);
            hb[b][r][cg + 8*p] = u;
        }
    };

    auto hblur = [&](int b) {
        hrow(b, r0_, xv0, yv0);
        if (p1) hrow(b, r1_, xv1, yv1);
    };

    /* ---- v-blur + SSIM for one rowgroup from LDS buf b ---- */
    auto p2group = [&](int b, int rbase) {
        h2 acc[2][4];
        #pragma unroll
        for (int o = 0; o < 2; ++o)
            #pragma unroll
            for (int f = 0; f < 4; ++f)
                acc[o][f] = (h2){(f16)0, (f16)0};
        #pragma unroll
        for (int j = 0; j < 12; ++j) {
            uint4 u = hb[b][rbase + j][idx];
            h2 f0 = uph(u.x), f1 = uph(u.y), f2 = uph(u.z), f3 = uph(u.w);
            #pragma unroll
            for (int o = 0; o < 2; ++o) {
                int k = j - o;
                if (k >= 0 && k < WIN) {
                    h2 wk = uph(W.hw[k]);
                    acc[o][0] += wk * f0;
                    acc[o][1] += wk * f1;
                    acc[o][2] += wk * f2;
                    acc[o][3] += wk * f3;
                }
            }
        }
        const float C1 = 0.01f * 0.01f;
        const float C2 = 0.03f * 0.03f;
        #pragma unroll
        for (int o = 0; o < 2; ++o) {
            #pragma unroll
            for (int p = 0; p < 2; ++p) {
                h2 m  = acc[o][2*p];               /* {mu_x, mu_y}   */
                h2 se = acc[o][2*p + 1];           /* {E[ss], E[xy]} */
                float mux = (float)m[0];
                float muy = (float)m[1];
                float es  = (float)se[0];
                float exy = (float)se[1];
                float mux2 = mux*mux, muy2 = muy*muy, muxy = mux*muy;
                float num = (2.f*muxy + C1) * (2.f*(exy - muxy) + C2);
                float den = (mux2 + muy2 + C1) * ((es - mux2 - muy2) + C2);
                local += num * __builtin_amdgcn_rcpf(den + 1e-8f);
            }
        }
    };

    auto phase2 = [&](int b) {
        p2group(b, rbaseA);
        p2group(b, rbaseB);
    };

    /* ---- prologue: tile 0 into buf 0; tile 1 loads in flight ---- */
    prefetch(0);
    hblur(0);
    prefetch(1);
    bar_lds();

    /* ---- main loop: ONE barrier per tile (8-wave scope) ---- */
    for (int t = 0; t < TPB; ++t) {
        if (t + 1 < TPB) {
            hblur((t + 1) & 1);       /* consumes regs (tile t+1) */
            if (t + 2 < TPB) {
                prefetch(t + 2);      /* refill regs; in flight over phase2 */
                __builtin_amdgcn_sched_barrier(0);
            }
        }
        phase2(t & 1);                /* reads other parity: no hazard */
        bar_lds();
    }

    /* ---- block reduce: one partial per block ---- */
    #pragma unroll
    for (int off = 32; off > 0; off >>= 1)
        local += __shfl_down(local, off, 64);
    if ((tid & 63) == 0) wsum[tid >> 6] = local;
    __syncthreads();
    if (tid == 0) {
        float bs = 0.f;
        #pragma unroll
        for (int wv = 0; wv < 8; ++wv) bs += wsum[wv];
        if (USE_ATOMIC) {
            atomicAdd(outp, bs);
        } else {
            outp[blockIdx.x] = bs;
        }
    }
}

// ---------------- Final reduce: 512 partials -> out[0], one block -----------
__global__ void __launch_bounds__(256) reduce_kernel(
        const float* __restrict__ partial, float* __restrict__ out) {
    __shared__ float wsum[4];
    const int tid = threadIdx.x;
    float s = 0.f;
    for (int i = tid; i < PBLK; i += 256) s += partial[i];
    #pragma unroll
    for (int off = 32; off > 0; off >>= 1)
        s += __shfl_down(s, off, 64);
    if ((tid & 63) == 0) wsum[tid >> 6] = s;
    __syncthreads();
    if (tid == 0)
        out[0] = 1.0f - (wsum[0] + wsum[1] + wsum[2] + wsum[3]) * (float)(1.0 / NPIX);
}

extern "C" void kernel_launch(void* const* d_in, const int* in_sizes, int n_in,
                              void* d_out, int out_size, void* d_ws, size_t ws_size,
                              hipStream_t stream) {
    const float* x = (const float*)d_in[0];
    const float* y = (const float*)d_in[1];
    float* out = (float*)d_out;

    /* fp32 Gaussian weights */
    double g[WIN], s = 0.0;
    for (int i = 0; i < WIN; ++i) {
        double d = (double)(i - WIN / 2);
        g[i] = exp(-(d * d) / (2.0 * 1.5 * 1.5));
        s += g[i];
    }
    float wf[WIN];
    for (int i = 0; i < WIN; ++i) wf[i] = (float)(g[i] / s);

    /* pack to fp16 {w,w}; renormalize center tap so fp16 weight sum == 1 */
    GaussW gw;
    _Float16 wh[WIN];
    double hsum = 0.0;
    for (int i = 0; i < WIN; ++i) { wh[i] = (_Float16)wf[i]; hsum += (double)(float)wh[i]; }
    wh[WIN/2] = (_Float16)((float)wh[WIN/2] + (float)(1.0 - hsum));
    for (int i = 0; i < WIN; ++i) {
        unsigned short b = __builtin_bit_cast(unsigned short, wh[i]);
        gw.hw[i] = (unsigned)b | ((unsigned)b << 16);
    }

    if (ws_size >= (size_t)PBLK * sizeof(float)) {
        float* partial = (float*)d_ws;
        hipLaunchKernelGGL((fused_ssim<0>), dim3(PBLK), dim3(512),
                           0, stream, x, y, partial, gw);
        hipLaunchKernelGGL(reduce_kernel, dim3(1), dim3(256), 0, stream,
                           partial, out);
    } else {
        hipLaunchKernelGGL(zero_kernel, dim3(1), dim3(64), 0, stream, out);
        hipLaunchKernelGGL((fused_ssim<1>), dim3(PBLK), dim3(512),
                           0, stream, x, y, out, gw);
        hipLaunchKernelGGL(finish_kernel, dim3(1), dim3(64), 0, stream, out);
    }
}

// Round 17
// 146.523 us; speedup vs baseline: 1.0287x; 1.0287x over previous
//
#include <hip/hip_runtime.h>
#include <cmath>

#define WIN 11
#define HALO 5
#define IMG 512
#define NIMG 48
#define TS 64                         /* output tile: 64x64 */
#define HR (TS + 2*HALO)              /* 74 h-blurred rows held in LDS */
#define NTILE (IMG/TS)                /* 8 tiles per axis */
#define NTT (NIMG*NTILE*NTILE)        /* 3072 tiles total */
#define PBLK 512                      /* persistent blocks: ALL resident */
#define TPB (NTT/PBLK)                /* 6 tiles per block */
#define NPIX (16.0 * 3.0 * 512.0 * 512.0)

typedef _Float16 f16;
typedef _Float16 h2 __attribute__((ext_vector_type(2)));

/* packed fp16 {w,w} weights, built on host -> kernarg -> SGPR operands */
struct GaussW { unsigned hw[WIN]; };

__device__ __forceinline__ unsigned pk2(float a, float b) {
    auto h = __builtin_amdgcn_cvt_pkrtz(a, b);
    return __builtin_bit_cast(unsigned, h);
}
__device__ __forceinline__ h2 uph(unsigned u) {
    return __builtin_bit_cast(h2, u);
}
__device__ __forceinline__ unsigned dnh(h2 v) {
    return __builtin_bit_cast(unsigned, v);
}

/* barrier that orders LDS only: does NOT drain vmcnt, so register-prefetch
   global loads stay in flight across it. */
__device__ __forceinline__ void bar_lds() {
    asm volatile("s_waitcnt lgkmcnt(0)" ::: "memory");
    __builtin_amdgcn_s_barrier();
}

__global__ void __launch_bounds__(64) zero_kernel(float* out) {
    if (threadIdx.x == 0) out[0] = 0.f;
}

__global__ void __launch_bounds__(64) finish_kernel(float* out) {
    if (threadIdx.x == 0)
        out[0] = 1.0f - out[0] * (float)(1.0 / NPIX);
}

// ---- Persistent fused SSIM: 512-thr blocks, 2 co-resident/CU, no spill ----
// R16 post-mortem: the co-resident experiment was masked by VGPR spill
// (dual xv0/xv1 buffers vs 64-VGPR budget -> WRITE_SIZE 16KB->2MB scratch,
// occupancy 33%, dur 63.5).  Co-residency itself is still the best lever:
// R2's 2-block config showed VALUBusy 60% vs 43-46% for all 1-block
// persistent variants, and dur ~= fixed 28us VALU_time / VALUBusy.
// This version: SINGLE xv/yv register buffer.  Phase 1 = pass-0 (rows
// 0..63, all 512 thr, prefetch-pipelined) + pass-1 (rows 64..73, threads
// 0..79, loaded inline -- 13.5% of loads unpipelined, 1.25 waves).  Keeps
// R15's dbuf hb[2] + one lgkm-only barrier per tile.  LDS 2x75.8KB =
// 151.5KB -> exactly 2 blocks/CU; 512 blocks = zero tail.
template<int USE_ATOMIC>
__global__ void __launch_bounds__(512, 4) fused_ssim(
        const float* __restrict__ xin, const float* __restrict__ yin,
        float* __restrict__ outp, GaussW W) {
    __shared__ uint4 hb[2][HR][32];   /* 2 * 74 * 512B = 75,776 B */
    __shared__ float wsum[8];
    const int tid = threadIdx.x;
    /* phase-1 mapping: 8 cols/thread x 64 rows (pass 0); rows 64..73 by
       threads 0..79 (pass 1, inline loads) */
    const int cg = tid & 7;
    const int rr = tid >> 3;          /* 0..63 */
    /* phase-2 mapping: 32 col-pair slots x 16 threads' 2 rowgroups */
    const int idx    = tid & 31;
    const int rbaseA = (tid >> 5) * 2;         /* output rows 0..31  */
    const int rbaseB = rbaseA + 32;            /* output rows 32..63 */

    const int t0 = blockIdx.x * TPB;

    float xv[18], yv[18];             /* single prefetch buffer */
    float local = 0.f;

    /* ---- tile coords ---- */
    auto tcoords = [&](int t, int& img, int& ty, int& tx) {
        const int tg = t0 + t;
        img = tg >> 6;
        const int rem = tg & 63;
        ty = rem >> 3;
        tx = rem & 7;
    };

    /* ---- load one 18-col row window into a register buffer ---- */
    auto loadrow = [&](int img, int ty, int tx, int r, float* xv_, float* yv_) {
        const float* xb = xin + (size_t)img * (IMG * IMG);
        const float* yb = yin + (size_t)img * (IMG * IMG);
        const int gy  = ty * TS - HALO + r;
        const int gx0 = tx * TS + cg * 8 - HALO;
        const bool rowok = ((unsigned)gy < IMG);
        const float* xr = xb + (size_t)gy * IMG;
        const float* yr = yb + (size_t)gy * IMG;
        if (rowok && gx0 >= 0 && gx0 + 17 < IMG) {
            xv_[0] = xr[gx0];  yv_[0] = yr[gx0];
            #pragma unroll
            for (int q = 0; q < 4; ++q) {          /* 16B-aligned float4s */
                float4 a = *(const float4*)(xr + gx0 + 1 + 4*q);
                float4 b = *(const float4*)(yr + gx0 + 1 + 4*q);
                xv_[1+4*q]=a.x; xv_[2+4*q]=a.y; xv_[3+4*q]=a.z; xv_[4+4*q]=a.w;
                yv_[1+4*q]=b.x; yv_[2+4*q]=b.y; yv_[3+4*q]=b.z; yv_[4+4*q]=b.w;
            }
            xv_[17] = xr[gx0 + 17];  yv_[17] = yr[gx0 + 17];
        } else {
            #pragma unroll
            for (int j = 0; j < 18; ++j) {
                int gx = gx0 + j;
                bool ok = rowok && ((unsigned)gx < IMG);
                xv_[j] = ok ? xr[gx] : 0.f;
                yv_[j] = ok ? yr[gx] : 0.f;
            }
        }
    };

    /* ---- issue pass-0 global loads for tile t into xv/yv ---- */
    auto prefetch = [&](int t) {
        int img, ty, tx;
        tcoords(t, img, ty, tx);
        loadrow(img, ty, tx, rr, xv, yv);
    };

    /* ---- packed fp16 h-blur of one register window -> LDS row ---- */
    auto hrow = [&](int b, int r, const float* xv_, const float* yv_) {
        h2 a0[8], a1[8];
        #pragma unroll
        for (int o = 0; o < 8; ++o) {
            a0[o] = (h2){(f16)0, (f16)0};
            a1[o] = (h2){(f16)0, (f16)0};
        }
        #pragma unroll
        for (int j = 0; j < 18; ++j) {
            float xs = xv_[j], ys = yv_[j];
            h2 c0 = uph(pk2(xs, ys));
            h2 c1 = uph(pk2(fmaf(xs, xs, ys * ys), xs * ys));
            #pragma unroll
            for (int o = 0; o < 8; ++o) {
                int k = j - o;
                if (k >= 0 && k < WIN) {
                    h2 wk = uph(W.hw[k]);          /* SGPR operand */
                    a0[o] += wk * c0;
                    a1[o] += wk * c1;
                }
            }
        }
        #pragma unroll
        for (int p = 0; p < 4; ++p) {
            uint4 u;
            u.x = dnh(a0[2*p]);     u.y = dnh(a1[2*p]);
            u.z = dnh(a0[2*p + 1]); u.w = dnh(a1[2*p + 1]);
            hb[b][r][cg + 8*p] = u;
        }
    };

    /* ---- full h-blur of tile t into LDS buf b ---- */
    auto hblur = [&](int b, int t) {
        hrow(b, rr, xv, yv);          /* pass 0: rows 0..63 from prefetch */
        if (tid < 80) {               /* pass 1: rows 64..73, inline loads */
            int img, ty, tx;
            tcoords(t, img, ty, tx);
            float xw[18], yw[18];
            loadrow(img, ty, tx, 64 + (tid >> 3), xw, yw);
            hrow(b, 64 + (tid >> 3), xw, yw);
        }
    };

    /* ---- v-blur + SSIM for one rowgroup from LDS buf b ---- */
    auto p2group = [&](int b, int rbase) {
        h2 acc[2][4];
        #pragma unroll
        for (int o = 0; o < 2; ++o)
            #pragma unroll
            for (int f = 0; f < 4; ++f)
                acc[o][f] = (h2){(f16)0, (f16)0};
        #pragma unroll
        for (int j = 0; j < 12; ++j) {
            uint4 u = hb[b][rbase + j][idx];
            h2 f0 = uph(u.x), f1 = uph(u.y), f2 = uph(u.z), f3 = uph(u.w);
            #pragma unroll
            for (int o = 0; o < 2; ++o) {
                int k = j - o;
                if (k >= 0 && k < WIN) {
                    h2 wk = uph(W.hw[k]);
                    acc[o][0] += wk * f0;
                    acc[o][1] += wk * f1;
                    acc[o][2] += wk * f2;
                    acc[o][3] += wk * f3;
                }
            }
        }
        const float C1 = 0.01f * 0.01f;
        const float C2 = 0.03f * 0.03f;
        #pragma unroll
        for (int o = 0; o < 2; ++o) {
            #pragma unroll
            for (int p = 0; p < 2; ++p) {
                h2 m  = acc[o][2*p];               /* {mu_x, mu_y}   */
                h2 se = acc[o][2*p + 1];           /* {E[ss], E[xy]} */
                float mux = (float)m[0];
                float muy = (float)m[1];
                float es  = (float)se[0];
                float exy = (float)se[1];
                float mux2 = mux*mux, muy2 = muy*muy, muxy = mux*muy;
                float num = (2.f*muxy + C1) * (2.f*(exy - muxy) + C2);
                float den = (mux2 + muy2 + C1) * ((es - mux2 - muy2) + C2);
                local += num * __builtin_amdgcn_rcpf(den + 1e-8f);
            }
        }
    };

    auto phase2 = [&](int b) {
        p2group(b, rbaseA);
        p2group(b, rbaseB);
    };

    /* ---- prologue: tile 0 into buf 0; tile 1 loads in flight ---- */
    prefetch(0);
    hblur(0, 0);
    prefetch(1);
    bar_lds();

    /* ---- main loop: ONE barrier per tile (8-wave scope) ---- */
    for (int t = 0; t < TPB; ++t) {
        if (t + 1 < TPB) {
            hblur((t + 1) & 1, t + 1);   /* consumes regs (tile t+1) */
            if (t + 2 < TPB) {
                prefetch(t + 2);      /* refill regs; in flight over phase2 */
                __builtin_amdgcn_sched_barrier(0);
            }
        }
        phase2(t & 1);                /* reads other parity: no hazard */
        bar_lds();
    }

    /* ---- block reduce: one partial per block ---- */
    #pragma unroll
    for (int off = 32; off > 0; off >>= 1)
        local += __shfl_down(local, off, 64);
    if ((tid & 63) == 0) wsum[tid >> 6] = local;
    __syncthreads();
    if (tid == 0) {
        float bs = 0.f;
        #pragma unroll
        for (int wv = 0; wv < 8; ++wv) bs += wsum[wv];
        if (USE_ATOMIC) {
            atomicAdd(outp, bs);
        } else {
            outp[blockIdx.x] = bs;
        }
    }
}

// ---------------- Final reduce: 512 partials -> out[0], one block -----------
__global__ void __launch_bounds__(256) reduce_kernel(
        const float* __restrict__ partial, float* __restrict__ out) {
    __shared__ float wsum[4];
    const int tid = threadIdx.x;
    float s = 0.f;
    for (int i = tid; i < PBLK; i += 256) s += partial[i];
    #pragma unroll
    for (int off = 32; off > 0; off >>= 1)
        s += __shfl_down(s, off, 64);
    if ((tid & 63) == 0) wsum[tid >> 6] = s;
    __syncthreads();
    if (tid == 0)
        out[0] = 1.0f - (wsum[0] + wsum[1] + wsum[2] + wsum[3]) * (float)(1.0 / NPIX);
}

extern "C" void kernel_launch(void* const* d_in, const int* in_sizes, int n_in,
                              void* d_out, int out_size, void* d_ws, size_t ws_size,
                              hipStream_t stream) {
    const float* x = (const float*)d_in[0];
    const float* y = (const float*)d_in[1];
    float* out = (float*)d_out;

    /* fp32 Gaussian weights */
    double g[WIN], s = 0.0;
    for (int i = 0; i < WIN; ++i) {
        double d = (double)(i - WIN / 2);
        g[i] = exp(-(d * d) / (2.0 * 1.5 * 1.5));
        s += g[i];
    }
    float wf[WIN];
    for (int i = 0; i < WIN; ++i) wf[i] = (float)(g[i] / s);

    /* pack to fp16 {w,w}; renormalize center tap so fp16 weight sum == 1 */
    GaussW gw;
    _Float16 wh[WIN];
    double hsum = 0.0;
    for (int i = 0; i < WIN; ++i) { wh[i] = (_Float16)wf[i]; hsum += (double)(float)wh[i]; }
    wh[WIN/2] = (_Float16)((float)wh[WIN/2] + (float)(1.0 - hsum));
    for (int i = 0; i < WIN; ++i) {
        unsigned short b = __builtin_bit_cast(unsigned short, wh[i]);
        gw.hw[i] = (unsigned)b | ((unsigned)b << 16);
    }

    if (ws_size >= (size_t)PBLK * sizeof(float)) {
        float* partial = (float*)d_ws;
        hipLaunchKernelGGL((fused_ssim<0>), dim3(PBLK), dim3(512),
                           0, stream, x, y, partial, gw);
        hipLaunchKernelGGL(reduce_kernel, dim3(1), dim3(256), 0, stream,
                           partial, out);
    } else {
        hipLaunchKernelGGL(zero_kernel, dim3(1), dim3(64), 0, stream, out);
        hipLaunchKernelGGL((fused_ssim<1>), dim3(PBLK), dim3(512),
                           0, stream, x, y, out, gw);
        hipLaunchKernelGGL(finish_kernel, dim3(1), dim3(64), 0, stream, out);
    }
}